// Round 2
// baseline (121.730 us; speedup 1.0000x reference)
//
#include <hip/hip_runtime.h>

// RNN_classifier: L=128 sequential steps over D=262144 independent columns,
// then out[t] = sigmoid(dot(x_bar[t], fc_w) + fc_b), out_size = 128 (fp32).
//
// Latency-bound fix (R2): 1 scalar column/thread -> 4096 waves (16/CU),
// depth-2 register prefetch -> ~10 MB in flight chip-wide.

#define L     128
#define DCOLS 262144
#define TPB   256
#define NWAVE (TPB / 64)
#define NBLK  (DCOLS / TPB)        // 1024 blocks, 1 float per thread

__device__ __forceinline__ float wred(float v) {
#pragma unroll
    for (int o = 32; o > 0; o >>= 1) v += __shfl_xor(v, o, 64);
    return v;
}

__device__ __forceinline__ float rcpf(float x) { return __builtin_amdgcn_rcpf(x); }

__device__ __forceinline__ float ftanh(float a) {
    a = fminf(fmaxf(a, -15.f), 15.f);          // avoid exp overflow -> NaN
    float e = __expf(-2.f * a);                // v_exp_f32
    return (1.f - e) * rcpf(1.f + e);
}

__device__ __forceinline__ float fsig(float z) {
    return rcpf(1.f + __expf(-z));             // inf-safe: 1/(1+inf) = 0
}

__global__ __launch_bounds__(TPB) void rnn_main(
    const float* __restrict__ x,  const float* __restrict__ wx,
    const float* __restrict__ wg, const float* __restrict__ wu,
    const float* __restrict__ m,  const float* __restrict__ fcw,
    float* __restrict__ part)
{
    __shared__ float lacc[NWAVE][L];
    const int tid  = threadIdx.x;
    const int lane = tid & 63;
    const int wid  = tid >> 6;
    const int col  = blockIdx.x * TPB + tid;

    const float* px  = x  + col;
    const float* pm  = m  + col;
    const float* pwx = wx + col;
    const float* pwu = wu + col;
    const float* pwg = wg + col;

    const float fw = fcw[col];

    // ---- t = 0 ----
    float x0  = px[0];
    float wx0 = pwx[0];
    float wg0 = pwg[0];

    float h0 = ftanh(x0 * wx0);
    float h  = h0;
    float xb = h0 * wg0 + x0;                  // xbar1 (carry)

    {   // x_bar[0] = x[0]
        float s = wred(x0 * fw);
        if (lane == 0) lacc[wid][0] = s;
    }

    // prefetch t=1 into A, t=2 into B
    float Ax = px[DCOLS],  Am = pm[DCOLS],  Awx = pwx[DCOLS],
          Awu = pwu[DCOLS], Awg = pwg[DCOLS];
    float Bx = px[2*DCOLS], Bm = pm[2*DCOLS], Bwx = pwx[2*DCOLS],
          Bwu = pwu[2*DCOLS], Bwg = pwg[2*DCOLS];

#define STEP(T, XR, MR, WXR, WUR, WGR)                                   \
    {                                                                    \
        float s = wred(xb * fw);               /* emit x_bar[T] */       \
        if (lane == 0) lacc[wid][(T)] = s;                               \
        float xt = (XR) * (MR) + xb * (1.f - (MR));                      \
        float u  = ftanh(xt * (WXR));                                    \
        float f  = fsig(h + u * (WUR)) * (MR);                           \
        float hn = f * h + (1.f - f) * u;                                \
        h  = fmaxf(hn, h0);                    /* h0 + relu(h-h0) */     \
        xb = h * (WGR) + xt;                                             \
    }

    int t = 1;
    for (; t + 1 < L; t += 2) {
        {   // step t (A regs), prefetch t+2 into A
            float xc = Ax, mc = Am, wxc = Awx, wuc = Awu, wgc = Awg;
            if (t + 2 < L) {
                const long o = (long)(t + 2) * DCOLS;
                Ax = px[o]; Am = pm[o]; Awx = pwx[o]; Awu = pwu[o]; Awg = pwg[o];
            }
            STEP(t, xc, mc, wxc, wuc, wgc);
        }
        {   // step t+1 (B regs), prefetch t+3 into B
            float xc = Bx, mc = Bm, wxc = Bwx, wuc = Bwu, wgc = Bwg;
            if (t + 3 < L) {
                const long o = (long)(t + 3) * DCOLS;
                Bx = px[o]; Bm = pm[o]; Bwx = pwx[o]; Bwu = pwu[o]; Bwg = pwg[o];
            }
            STEP(t + 1, xc, mc, wxc, wuc, wgc);
        }
    }
    // t == 127: last step, data sits in A regs (prefetched at t=125)
    STEP(t, Ax, Am, Awx, Awu, Awg);
#undef STEP

    __syncthreads();
    if (tid < L) {
        float s = 0.f;
#pragma unroll
        for (int w = 0; w < NWAVE; ++w) s += lacc[w][tid];
        part[blockIdx.x * L + tid] = s;
    }
}

__global__ __launch_bounds__(64) void rnn_finish(
    const float* __restrict__ part, const float* __restrict__ fcb,
    float* __restrict__ out)
{
    const int t    = blockIdx.x;   // 0..127
    const int lane = threadIdx.x;  // 64
    float s = 0.f;
    for (int b = lane; b < NBLK; b += 64) s += part[b * L + t];
    s = wred(s);
    if (lane == 0) out[t] = fsig(s + fcb[0]);
}

extern "C" void kernel_launch(void* const* d_in, const int* in_sizes, int n_in,
                              void* d_out, int out_size, void* d_ws, size_t ws_size,
                              hipStream_t stream) {
    // setup_inputs order: x, weight_x, weight_g, weight_u, mask, fc_w, fc_b
    const float* x   = (const float*)d_in[0];
    const float* wx  = (const float*)d_in[1];
    const float* wg  = (const float*)d_in[2];
    const float* wu  = (const float*)d_in[3];
    const float* m   = (const float*)d_in[4];
    const float* fcw = (const float*)d_in[5];
    const float* fcb = (const float*)d_in[6];
    float* out  = (float*)d_out;
    float* part = (float*)d_ws;    // NBLK * L floats = 512 KB

    rnn_main<<<NBLK, TPB, 0, stream>>>(x, wx, wg, wu, m, fcw, part);
    rnn_finish<<<L, 64, 0, stream>>>(part, fcb, out);
}